// Round 3
// baseline (316.043 us; speedup 1.0000x reference)
//
#include <hip/hip_runtime.h>
#include <hip/hip_bf16.h>

// Problem constants
#define B_ 4096
#define T_ 256
#define F_ 64
#define H_ 128
#define S_ 32

typedef __attribute__((ext_vector_type(8))) short bf16x8;
typedef __attribute__((ext_vector_type(4))) float f32x4;

#define HS 136   // h LDS row stride (bf16 elems): 272B ≡ 4 mod 32 banks (~2-way, ~free)

#define K1f (-1.4426950408889634f)   // -log2(e)
#define K2f (-2.8853900817779268f)   // -2*log2(e)

__device__ __forceinline__ float bf2f(unsigned short u) {
    unsigned v = (unsigned)u << 16;
    return __builtin_bit_cast(float, v);
}
__device__ __forceinline__ short f2bs(float f) {
    return (short)__bfloat16_as_ushort(__float2bfloat16(f));
}

struct XReg { float4 a, b, c, d; };   // one step's per-lane x slice (16 fp32)

// One LSTM step (phase).
//   XR : register x slice for step t (read, then reloaded for step TL)
//   HR : LDS buffer holding h_t ; HW : LDS buffer for h_{t+1}
// Ends with lgkmcnt(0) + raw s_barrier (NO vmcnt drain -> x loads stay in flight).
#define PHASE(XR, HR, HW, TL)                                                     \
  {                                                                               \
    /* h_t fragments: issue ds_reads first (latency ~120cy) */                    \
    bf16x8 a0 = *(const bf16x8*)&HR[fhb];                                         \
    bf16x8 a1 = *(const bf16x8*)&HR[fhb + 32];                                    \
    bf16x8 a2 = *(const bf16x8*)&HR[fhb + 64];                                    \
    bf16x8 a3 = *(const bf16x8*)&HR[fhb + 96];                                    \
    /* x_t frags from registers (vmcnt counted wait, loaded 2 phases ago) */      \
    bf16x8 fx0, fx1;                                                              \
    fx0[0] = f2bs(XR.a.x); fx0[1] = f2bs(XR.a.y); fx0[2] = f2bs(XR.a.z);          \
    fx0[3] = f2bs(XR.a.w); fx0[4] = f2bs(XR.b.x); fx0[5] = f2bs(XR.b.y);          \
    fx0[6] = f2bs(XR.b.z); fx0[7] = f2bs(XR.b.w);                                 \
    fx1[0] = f2bs(XR.c.x); fx1[1] = f2bs(XR.c.y); fx1[2] = f2bs(XR.c.z);          \
    fx1[3] = f2bs(XR.c.w); fx1[4] = f2bs(XR.d.x); fx1[5] = f2bs(XR.d.y);          \
    fx1[6] = f2bs(XR.d.z); fx1[7] = f2bs(XR.d.w);                                 \
    /* reload XR for step TL (in flight across 2 phases; no barrier drain) */     \
    { const float* lp_ = gxl + (size_t)(TL) * F_;                                 \
      XR.a = *(const float4*)(lp_);                                               \
      XR.b = *(const float4*)(lp_ + 4);                                           \
      XR.c = *(const float4*)(lp_ + 32);                                          \
      XR.d = *(const float4*)(lp_ + 36); }                                        \
    /* seed acc with x-part (register-only; overlaps h ds_read latency) */        \
    f32x4 ac0, ac1, ac2, ac3;                                                     \
    ac0 = __builtin_amdgcn_mfma_f32_16x16x32_bf16(wf[0][0], fx0, z4, 0, 0, 0);    \
    ac1 = __builtin_amdgcn_mfma_f32_16x16x32_bf16(wf[1][0], fx0, z4, 0, 0, 0);    \
    ac2 = __builtin_amdgcn_mfma_f32_16x16x32_bf16(wf[2][0], fx0, z4, 0, 0, 0);    \
    ac3 = __builtin_amdgcn_mfma_f32_16x16x32_bf16(wf[3][0], fx0, z4, 0, 0, 0);    \
    ac0 = __builtin_amdgcn_mfma_f32_16x16x32_bf16(wf[0][1], fx1, ac0, 0, 0, 0);   \
    ac1 = __builtin_amdgcn_mfma_f32_16x16x32_bf16(wf[1][1], fx1, ac1, 0, 0, 0);   \
    ac2 = __builtin_amdgcn_mfma_f32_16x16x32_bf16(wf[2][1], fx1, ac2, 0, 0, 0);   \
    ac3 = __builtin_amdgcn_mfma_f32_16x16x32_bf16(wf[3][1], fx1, ac3, 0, 0, 0);   \
    /* h-part */                                                                  \
    ac0 = __builtin_amdgcn_mfma_f32_16x16x32_bf16(wf[0][2], a0, ac0, 0, 0, 0);    \
    ac1 = __builtin_amdgcn_mfma_f32_16x16x32_bf16(wf[1][2], a0, ac1, 0, 0, 0);    \
    ac2 = __builtin_amdgcn_mfma_f32_16x16x32_bf16(wf[2][2], a0, ac2, 0, 0, 0);    \
    ac3 = __builtin_amdgcn_mfma_f32_16x16x32_bf16(wf[3][2], a0, ac3, 0, 0, 0);    \
    ac0 = __builtin_amdgcn_mfma_f32_16x16x32_bf16(wf[0][3], a1, ac0, 0, 0, 0);    \
    ac1 = __builtin_amdgcn_mfma_f32_16x16x32_bf16(wf[1][3], a1, ac1, 0, 0, 0);    \
    ac2 = __builtin_amdgcn_mfma_f32_16x16x32_bf16(wf[2][3], a1, ac2, 0, 0, 0);    \
    ac3 = __builtin_amdgcn_mfma_f32_16x16x32_bf16(wf[3][3], a1, ac3, 0, 0, 0);    \
    ac0 = __builtin_amdgcn_mfma_f32_16x16x32_bf16(wf[0][4], a2, ac0, 0, 0, 0);    \
    ac1 = __builtin_amdgcn_mfma_f32_16x16x32_bf16(wf[1][4], a2, ac1, 0, 0, 0);    \
    ac2 = __builtin_amdgcn_mfma_f32_16x16x32_bf16(wf[2][4], a2, ac2, 0, 0, 0);    \
    ac3 = __builtin_amdgcn_mfma_f32_16x16x32_bf16(wf[3][4], a2, ac3, 0, 0, 0);    \
    ac0 = __builtin_amdgcn_mfma_f32_16x16x32_bf16(wf[0][5], a3, ac0, 0, 0, 0);    \
    ac1 = __builtin_amdgcn_mfma_f32_16x16x32_bf16(wf[1][5], a3, ac1, 0, 0, 0);    \
    ac2 = __builtin_amdgcn_mfma_f32_16x16x32_bf16(wf[2][5], a3, ac2, 0, 0, 0);    \
    ac3 = __builtin_amdgcn_mfma_f32_16x16x32_bf16(wf[3][5], a3, ac3, 0, 0, 0);    \
    /* LSTM cell update + h write */                                              \
    float hn[4];                                                                  \
    _Pragma("unroll")                                                             \
    for (int q = 0; q < 4; ++q) {                                                 \
      const float ei = __builtin_amdgcn_exp2f(__builtin_fmaf(ac0[q], K1f, bs0[q])); \
      const float i_ = __builtin_amdgcn_rcpf(1.0f + ei);                          \
      const float ef = __builtin_amdgcn_exp2f(__builtin_fmaf(ac1[q], K1f, bs1[q])); \
      const float f_ = __builtin_amdgcn_rcpf(1.0f + ef);                          \
      const float eg = __builtin_amdgcn_exp2f(__builtin_fmaf(ac2[q], K2f, btn[q])); \
      const float g_ = __builtin_fmaf(2.0f, __builtin_amdgcn_rcpf(1.0f + eg), -1.0f); \
      const float eo = __builtin_amdgcn_exp2f(__builtin_fmaf(ac3[q], K1f, bs3[q])); \
      const float o_ = __builtin_amdgcn_rcpf(1.0f + eo);                          \
      const float cn = __builtin_fmaf(f_, c[q], i_ * g_);                         \
      c[q] = cn;                                                                  \
      const float ec = __builtin_amdgcn_exp2f(cn * K2f);                          \
      const float th = __builtin_fmaf(2.0f, __builtin_amdgcn_rcpf(1.0f + ec), -1.0f); \
      hn[q] = o_ * th;                                                            \
    }                                                                             \
    { unsigned lo = (unsigned)(unsigned short)f2bs(hn[0])                         \
                  | ((unsigned)(unsigned short)f2bs(hn[1]) << 16);                \
      unsigned hi = (unsigned)(unsigned short)f2bs(hn[2])                         \
                  | ((unsigned)(unsigned short)f2bs(hn[3]) << 16);                \
      uint2 uv; uv.x = lo; uv.y = hi;                                             \
      *(uint2*)&HW[hwo] = uv; }                                                   \
    asm volatile("s_waitcnt lgkmcnt(0)" ::: "memory");                            \
    __builtin_amdgcn_s_barrier();                                                 \
  }

__global__ __launch_bounds__(512, 2) void lstm_fused_kernel(
    const float* __restrict__ x,      // [B,T,F]
    const float* __restrict__ statik, // [B,S]
    const float* __restrict__ hs0,    // [B,H]
    const float* __restrict__ cs0,    // [B,H]
    const float* __restrict__ W_ih,   // [4H,F]
    const float* __restrict__ W_hh,   // [4H,H]
    const float* __restrict__ b_ih,   // [4H]
    const float* __restrict__ b_hh,   // [4H]
    const float* __restrict__ W_lin,  // [H+S]
    const float* __restrict__ b_lin,  // [1]
    float* __restrict__ out)          // [B]
{
    __shared__ unsigned short h_l[2][16 * HS];

    const int tid  = threadIdx.x;
    const int lane = tid & 63;
    const int w    = tid >> 6;         // wave 0..7
    const int b0   = blockIdx.x * 16;

    const int lrow = lane & 15;        // batch row (B-frag col / C col)
    const int lkb  = lane >> 4;        // k-group / C row-group
    const int n0q  = w * 16 + lkb * 4; // hidden-dim base owned by this lane

    // ---- one-time: weight fragments (A-operand) into registers, bf16 ----
    bf16x8 wf[4][6];
    #pragma unroll
    for (int g = 0; g < 4; ++g) {
        const int n = g * 128 + w * 16 + lrow;
        #pragma unroll
        for (int kt = 0; kt < 6; ++kt) {
            const int k0 = kt * 32 + lkb * 8;
            const float* src = (kt < 2) ? (W_ih + n * F_ + k0)
                                        : (W_hh + n * H_ + (k0 - 64));
            const float4 s0 = *(const float4*)(src);
            const float4 s1 = *(const float4*)(src + 4);
            bf16x8 v;
            v[0] = f2bs(s0.x); v[1] = f2bs(s0.y); v[2] = f2bs(s0.z); v[3] = f2bs(s0.w);
            v[4] = f2bs(s1.x); v[5] = f2bs(s1.y); v[6] = f2bs(s1.z); v[7] = f2bs(s1.w);
            wf[g][kt] = v;
        }
    }

    // ---- biases, pre-scaled into the exp2 argument ----
    float bs0[4], bs1[4], btn[4], bs3[4];
    #pragma unroll
    for (int g = 0; g < 4; ++g) {
        const float4 bi = *(const float4*)(b_ih + g * 128 + n0q);
        const float4 bh = *(const float4*)(b_hh + g * 128 + n0q);
        const float bq[4] = {bi.x + bh.x, bi.y + bh.y, bi.z + bh.z, bi.w + bh.w};
        #pragma unroll
        for (int q = 0; q < 4; ++q) {
            if (g == 0)      bs0[q] = bq[q] * K1f;
            else if (g == 1) bs1[q] = bq[q] * K1f;
            else if (g == 2) btn[q] = bq[q] * K2f;
            else             bs3[q] = bq[q] * K1f;
        }
    }

    // ---- c state: lane owns c[batch=lrow][n0q..n0q+3] ----
    float c[4];
    {
        const float4 cv = *(const float4*)(cs0 + (size_t)(b0 + lrow) * H_ + n0q);
        c[0] = cv.x; c[1] = cv.y; c[2] = cv.z; c[3] = cv.w;
    }

    // ---- per-lane x base: this lane's B-frag slice lives at f = lkb*8(+32) ----
    const float* gxl = x + (size_t)(b0 + lrow) * (T_ * F_) + lkb * 8;

    // ---- prologue: stage h0 to LDS (bf16), prefetch x_0 and x_1 ----
    {
        const int srow = tid >> 5;      // 0..15
        const int scp  = tid & 31;      // 0..31
        const float* hp = hs0 + (size_t)(b0 + srow) * H_ + scp * 2;
        const float2 hv0 = *(const float2*)(hp);
        const float2 hv1 = *(const float2*)(hp + 64);
        unsigned q0 = (unsigned)(unsigned short)f2bs(hv0.x)
                    | ((unsigned)(unsigned short)f2bs(hv0.y) << 16);
        unsigned q1 = (unsigned)(unsigned short)f2bs(hv1.x)
                    | ((unsigned)(unsigned short)f2bs(hv1.y) << 16);
        *(unsigned*)&h_l[0][srow * HS + scp * 2]      = q0;
        *(unsigned*)&h_l[0][srow * HS + 64 + scp * 2] = q1;
    }
    XReg xr0, xr1;
    xr0.a = *(const float4*)(gxl);
    xr0.b = *(const float4*)(gxl + 4);
    xr0.c = *(const float4*)(gxl + 32);
    xr0.d = *(const float4*)(gxl + 36);
    xr1.a = *(const float4*)(gxl + F_);
    xr1.b = *(const float4*)(gxl + F_ + 4);
    xr1.c = *(const float4*)(gxl + F_ + 32);
    xr1.d = *(const float4*)(gxl + F_ + 36);
    __syncthreads();

    // ---- step-invariant offsets (elements) ----
    const int fhb = lrow * HS + lkb * 8;
    const int hwo = lrow * HS + n0q;       // h write: 4 consecutive bf16 = 8B
    const f32x4 z4 = {0.0f, 0.0f, 0.0f, 0.0f};

    // ---- recurrence: 2 steps/iter, compile-time ping-pong + x reg ring ----
    for (int t = 0; t < T_; t += 2) {
        const int tl0 = (t + 2 < T_) ? t + 2 : T_ - 1;
        const int tl1 = (t + 3 < T_) ? t + 3 : T_ - 1;
        PHASE(xr0, h_l[0], h_l[1], tl0);
        PHASE(xr1, h_l[1], h_l[0], tl1);
    }

    // ---- head: out[b] = [h,static]@W_lin^T + b (h read as bf16) ----
    {
        const unsigned short* hf = h_l[0];
        const float wl0 = W_lin[lane];
        const float wl1 = W_lin[64 + lane];
        const float wl2 = (lane < S_) ? W_lin[128 + lane] : 0.0f;
        const float bl  = b_lin[0];
        #pragma unroll
        for (int rr = 0; rr < 2; ++rr) {
            const int r = w * 2 + rr;
            float p = bf2f(hf[r * HS + lane]) * wl0
                    + bf2f(hf[r * HS + 64 + lane]) * wl1;
            if (lane < S_) p += statik[(size_t)(b0 + r) * S_ + lane] * wl2;
            #pragma unroll
            for (int m = 32; m > 0; m >>= 1) p += __shfl_xor(p, m, 64);
            if (lane == 0) out[b0 + r] = p + bl;
        }
    }
}

extern "C" void kernel_launch(void* const* d_in, const int* in_sizes, int n_in,
                              void* d_out, int out_size, void* d_ws, size_t ws_size,
                              hipStream_t stream) {
    const float* x     = (const float*)d_in[0];
    const float* st    = (const float*)d_in[1];
    const float* hs0   = (const float*)d_in[2];
    const float* cs0   = (const float*)d_in[3];
    const float* W_ih  = (const float*)d_in[4];
    const float* W_hh  = (const float*)d_in[5];
    const float* b_ih  = (const float*)d_in[6];
    const float* b_hh  = (const float*)d_in[7];
    const float* W_lin = (const float*)d_in[8];
    const float* b_lin = (const float*)d_in[9];
    float* out = (float*)d_out;

    lstm_fused_kernel<<<dim3(B_ / 16), dim3(512), 0, stream>>>(
        x, st, hs0, cs0, W_ih, W_hh, b_ih, b_hh, W_lin, b_lin, out);
}

// Round 4
// 228.619 us; speedup vs baseline: 1.3824x; 1.3824x over previous
//
#include <hip/hip_runtime.h>
#include <hip/hip_bf16.h>

// Problem constants
#define B_ 4096
#define T_ 256
#define F_ 64
#define H_ 128
#define S_ 32

typedef __attribute__((ext_vector_type(8))) short bf16x8;
typedef __attribute__((ext_vector_type(4))) float f32x4;

#define K1f (-1.4426950408889634f)   // -log2(e)
#define K2f (-2.8853900817779268f)   // -2*log2(e)

#define MF(A, B, C) __builtin_amdgcn_mfma_f32_16x16x32_bf16((A), (B), (C), 0, 0, 0)

__device__ __forceinline__ float bf2f(unsigned short u) {
    unsigned v = (unsigned)u << 16;
    return __builtin_bit_cast(float, v);
}
__device__ __forceinline__ short f2bs(float f) {
    return (short)__bfloat16_as_ushort(__float2bfloat16(f));
}

// One LSTM step (phase p of a 4-phase unrolled iteration).
//  HR: LDS h buffer for h_t (read)   HW: LDS h buffer for h_{t+1} (write)
//  XW: x buffer receiving x_{t+2} (from xheld regs, loaded last phase)
//  XN: x buffer holding x_{t+1} (read at tail -> seed MFMAs for next step)
//  TLD: time index to load into xheld (t+3, clamped)
// Carried across phases: sd0..sd3 (x-part MFMA seeds), xheld, c[4].
// Ends with lgkmcnt(0) + raw s_barrier (vmcnt stays counted -> x load in flight).
#define PHASE(HR, HW, XW, XN, TLD)                                               \
  {                                                                              \
    const char* hr_ = (const char*)(HR);                                         \
    bf16x8 a0 = *(const bf16x8*)(hr_ + fh0);                                     \
    bf16x8 a1 = *(const bf16x8*)(hr_ + fh1);                                     \
    bf16x8 a2 = *(const bf16x8*)(hr_ + fh2);                                     \
    bf16x8 a3 = *(const bf16x8*)(hr_ + fh3);                                     \
    /* commit xheld (x_{t+2}) to XW; reload xheld for step TLD */                \
    { __hip_bfloat162 qx = __float22bfloat162_rn(xheld);                         \
      *(__hip_bfloat162*)((char*)(XW) + xws) = qx; }                             \
    xheld = *(const float2*)(gxs + (size_t)(TLD) * F_);                          \
    /* h-part MFMAs onto carried x seeds */                                      \
    f32x4 ac0 = sd0, ac1 = sd1, ac2 = sd2, ac3 = sd3;                            \
    ac0 = MF(wf[0][2], a0, ac0); ac1 = MF(wf[1][2], a0, ac1);                    \
    ac2 = MF(wf[2][2], a0, ac2); ac3 = MF(wf[3][2], a0, ac3);                    \
    ac0 = MF(wf[0][3], a1, ac0); ac1 = MF(wf[1][3], a1, ac1);                    \
    ac2 = MF(wf[2][3], a1, ac2); ac3 = MF(wf[3][3], a1, ac3);                    \
    ac0 = MF(wf[0][4], a2, ac0); ac1 = MF(wf[1][4], a2, ac1);                    \
    ac2 = MF(wf[2][4], a2, ac2); ac3 = MF(wf[3][4], a2, ac3);                    \
    ac0 = MF(wf[0][5], a3, ac0); ac1 = MF(wf[1][5], a3, ac1);                    \
    ac2 = MF(wf[2][5], a3, ac2); ac3 = MF(wf[3][5], a3, ac3);                    \
    /* LSTM cell update + h write */                                             \
    float hn[4];                                                                 \
    _Pragma("unroll")                                                            \
    for (int q = 0; q < 4; ++q) {                                                \
      const float ei = __builtin_amdgcn_exp2f(__builtin_fmaf(ac0[q], K1f, bs0[q])); \
      const float i_ = __builtin_amdgcn_rcpf(1.0f + ei);                         \
      const float ef = __builtin_amdgcn_exp2f(__builtin_fmaf(ac1[q], K1f, bs1[q])); \
      const float f_ = __builtin_amdgcn_rcpf(1.0f + ef);                         \
      const float eg = __builtin_amdgcn_exp2f(__builtin_fmaf(ac2[q], K2f, btn[q])); \
      const float g_ = __builtin_fmaf(2.0f, __builtin_amdgcn_rcpf(1.0f + eg), -1.0f); \
      const float eo = __builtin_amdgcn_exp2f(__builtin_fmaf(ac3[q], K1f, bs3[q])); \
      const float o_ = __builtin_amdgcn_rcpf(1.0f + eo);                         \
      const float cn = __builtin_fmaf(f_, c[q], i_ * g_);                        \
      c[q] = cn;                                                                 \
      const float ec = __builtin_amdgcn_exp2f(cn * K2f);                         \
      const float th = __builtin_fmaf(2.0f, __builtin_amdgcn_rcpf(1.0f + ec), -1.0f); \
      hn[q] = o_ * th;                                                           \
    }                                                                            \
    { float2 p0; p0.x = hn[0]; p0.y = hn[1];                                     \
      float2 p1; p1.x = hn[2]; p1.y = hn[3];                                     \
      __hip_bfloat162 b01 = __float22bfloat162_rn(p0);                           \
      __hip_bfloat162 b23 = __float22bfloat162_rn(p1);                           \
      uint2 uv; uv.x = *(unsigned*)&b01; uv.y = *(unsigned*)&b23;                \
      *(uint2*)((char*)(HW) + hwb) = uv; }                                       \
    /* next-step x seeds (buffer XN written >=2 phases ago: visible) */          \
    { const char* xn_ = (const char*)(XN);                                       \
      bf16x8 nf0 = *(const bf16x8*)(xn_ + fx0);                                  \
      bf16x8 nf1 = *(const bf16x8*)(xn_ + fx1);                                  \
      sd0 = MF(wf[0][0], nf0, z4); sd1 = MF(wf[1][0], nf0, z4);                  \
      sd2 = MF(wf[2][0], nf0, z4); sd3 = MF(wf[3][0], nf0, z4);                  \
      sd0 = MF(wf[0][1], nf1, sd0); sd1 = MF(wf[1][1], nf1, sd1);                \
      sd2 = MF(wf[2][1], nf1, sd2); sd3 = MF(wf[3][1], nf1, sd3); }              \
    asm volatile("s_waitcnt lgkmcnt(0)" ::: "memory");                           \
    __builtin_amdgcn_s_barrier();                                                \
  }

__global__ __launch_bounds__(512, 2) void lstm_fused_kernel(
    const float* __restrict__ x,      // [B,T,F]
    const float* __restrict__ statik, // [B,S]
    const float* __restrict__ hs0,    // [B,H]
    const float* __restrict__ cs0,    // [B,H]
    const float* __restrict__ W_ih,   // [4H,F]
    const float* __restrict__ W_hh,   // [4H,H]
    const float* __restrict__ b_ih,   // [4H]
    const float* __restrict__ b_hh,   // [4H]
    const float* __restrict__ W_lin,  // [H+S]
    const float* __restrict__ b_lin,  // [1]
    float* __restrict__ out)          // [B]
{
    // XOR-swizzled tiles (T2): byte ^= (row&7)<<4. Natural strides keep 16B
    // alignment for b128 frag reads; swizzle gives <=2-way bank aliasing.
    __shared__ __align__(16) unsigned short h_l[2][16 * 128];  // 256B rows
    __shared__ __align__(16) unsigned short x_l[4][16 * 64];   // 128B rows

    const int tid  = threadIdx.x;
    const int lane = tid & 63;
    const int w    = tid >> 6;         // wave 0..7
    const int b0   = blockIdx.x * 16;

    const int lrow = lane & 15;        // batch row (B-frag col / C col)
    const int lkb  = lane >> 4;        // k-group / C row-group
    const int n0q  = w * 16 + lkb * 4; // hidden-dim base owned by this lane

    // ---- one-time: weight fragments (A-operand) into registers, bf16 ----
    bf16x8 wf[4][6];
    #pragma unroll
    for (int g = 0; g < 4; ++g) {
        const int n = g * 128 + w * 16 + lrow;
        #pragma unroll
        for (int kt = 0; kt < 6; ++kt) {
            const int k0 = kt * 32 + lkb * 8;
            const float* src = (kt < 2) ? (W_ih + n * F_ + k0)
                                        : (W_hh + n * H_ + (k0 - 64));
            const float4 s0 = *(const float4*)(src);
            const float4 s1 = *(const float4*)(src + 4);
            bf16x8 v;
            v[0] = f2bs(s0.x); v[1] = f2bs(s0.y); v[2] = f2bs(s0.z); v[3] = f2bs(s0.w);
            v[4] = f2bs(s1.x); v[5] = f2bs(s1.y); v[6] = f2bs(s1.z); v[7] = f2bs(s1.w);
            wf[g][kt] = v;
        }
    }

    // ---- biases, pre-scaled into the exp2 argument ----
    float bs0[4], bs1[4], btn[4], bs3[4];
    #pragma unroll
    for (int g = 0; g < 4; ++g) {
        const float4 bi = *(const float4*)(b_ih + g * 128 + n0q);
        const float4 bh = *(const float4*)(b_hh + g * 128 + n0q);
        const float bq[4] = {bi.x + bh.x, bi.y + bh.y, bi.z + bh.z, bi.w + bh.w};
        #pragma unroll
        for (int q = 0; q < 4; ++q) {
            if (g == 0)      bs0[q] = bq[q] * K1f;
            else if (g == 1) bs1[q] = bq[q] * K1f;
            else if (g == 2) btn[q] = bq[q] * K2f;
            else             bs3[q] = bq[q] * K1f;
        }
    }

    // ---- c state: lane owns c[batch=lrow][n0q..n0q+3] ----
    float c[4];
    {
        const float4 cv = *(const float4*)(cs0 + (size_t)(b0 + lrow) * H_ + n0q);
        c[0] = cv.x; c[1] = cv.y; c[2] = cv.z; c[3] = cv.w;
    }

    // ---- step-invariant swizzled byte offsets ----
    const int fsw = (lrow & 7) << 4;
    const int fx0 = lrow * 128 + ((lkb * 16) ^ fsw);
    const int fx1 = lrow * 128 + ((64 + lkb * 16) ^ fsw);
    const int fh0 = lrow * 256 + ((0   + lkb * 16) ^ fsw);
    const int fh1 = lrow * 256 + ((64  + lkb * 16) ^ fsw);
    const int fh2 = lrow * 256 + ((128 + lkb * 16) ^ fsw);
    const int fh3 = lrow * 256 + ((192 + lkb * 16) ^ fsw);
    const int hwb = lrow * 256 + ((n0q * 2) ^ fsw);        // b64 h write

    const int srow = tid >> 5;          // 0..15 (staging row)
    const int scp  = tid & 31;          // 0..31 (float-pair col)
    const int ssw  = (srow & 7) << 4;
    const int xws  = srow * 128 + ((scp * 4) ^ ssw);       // b32 x stage write

    // ---- prologue: stage h0, x_0, x_1; prefetch x_2 into regs ----
    const float* gxs = x + (size_t)(b0 + srow) * (T_ * F_) + scp * 2;
    float2 xheld;
    {
        const float* hp = hs0 + (size_t)(b0 + srow) * H_ + scp * 2;
        const float2 hv0 = *(const float2*)(hp);
        const float2 hv1 = *(const float2*)(hp + 64);
        __hip_bfloat162 q0 = __float22bfloat162_rn(hv0);
        __hip_bfloat162 q1 = __float22bfloat162_rn(hv1);
        *(__hip_bfloat162*)((char*)h_l[0] + srow * 256 + ((scp * 4) ^ ssw))       = q0;
        *(__hip_bfloat162*)((char*)h_l[0] + srow * 256 + ((128 + scp * 4) ^ ssw)) = q1;

        const float2 x0 = *(const float2*)(gxs);
        const float2 x1 = *(const float2*)(gxs + F_);
        __hip_bfloat162 qa = __float22bfloat162_rn(x0);
        __hip_bfloat162 qb = __float22bfloat162_rn(x1);
        *(__hip_bfloat162*)((char*)x_l[0] + xws) = qa;
        *(__hip_bfloat162*)((char*)x_l[1] + xws) = qb;
        xheld = *(const float2*)(gxs + 2 * F_);
    }
    __syncthreads();

    const f32x4 z4 = {0.0f, 0.0f, 0.0f, 0.0f};

    // ---- initial x seeds for step 0 (from x_l[0]) ----
    f32x4 sd0, sd1, sd2, sd3;
    {
        const char* xn_ = (const char*)x_l[0];
        bf16x8 nf0 = *(const bf16x8*)(xn_ + fx0);
        bf16x8 nf1 = *(const bf16x8*)(xn_ + fx1);
        sd0 = MF(wf[0][0], nf0, z4); sd1 = MF(wf[1][0], nf0, z4);
        sd2 = MF(wf[2][0], nf0, z4); sd3 = MF(wf[3][0], nf0, z4);
        sd0 = MF(wf[0][1], nf1, sd0); sd1 = MF(wf[1][1], nf1, sd1);
        sd2 = MF(wf[2][1], nf1, sd2); sd3 = MF(wf[3][1], nf1, sd3);
    }

    // ---- recurrence: 4 phases/iter; x 4-buffer rotation, h ping-pong ----
    for (int t = 0; t < T_; t += 4) {
        const int t3 = (t + 3 < T_) ? t + 3 : T_ - 1;
        const int t4 = (t + 4 < T_) ? t + 4 : T_ - 1;
        const int t5 = (t + 5 < T_) ? t + 5 : T_ - 1;
        const int t6 = (t + 6 < T_) ? t + 6 : T_ - 1;
        PHASE(h_l[0], h_l[1], x_l[2], x_l[1], t3);
        PHASE(h_l[1], h_l[0], x_l[3], x_l[2], t4);
        PHASE(h_l[0], h_l[1], x_l[0], x_l[3], t5);
        PHASE(h_l[1], h_l[0], x_l[1], x_l[0], t6);
    }

    // ---- head: out[b] = [h,static]@W_lin^T + b (h_T in h_l[0], swizzled) ----
    {
        const char* hf = (const char*)h_l[0];
        const float wl0 = W_lin[lane];
        const float wl1 = W_lin[64 + lane];
        const float wl2 = (lane < S_) ? W_lin[128 + lane] : 0.0f;
        const float bl  = b_lin[0];
        #pragma unroll
        for (int rr = 0; rr < 2; ++rr) {
            const int r  = w * 2 + rr;
            const int rs = (r & 7) << 4;
            const unsigned short h0 =
                *(const unsigned short*)(hf + r * 256 + ((2 * lane) ^ rs));
            const unsigned short h1 =
                *(const unsigned short*)(hf + r * 256 + ((128 + 2 * lane) ^ rs));
            float p = bf2f(h0) * wl0 + bf2f(h1) * wl1;
            if (lane < S_) p += statik[(size_t)(b0 + r) * S_ + lane] * wl2;
            #pragma unroll
            for (int m = 32; m > 0; m >>= 1) p += __shfl_xor(p, m, 64);
            if (lane == 0) out[b0 + r] = p + bl;
        }
    }
}

extern "C" void kernel_launch(void* const* d_in, const int* in_sizes, int n_in,
                              void* d_out, int out_size, void* d_ws, size_t ws_size,
                              hipStream_t stream) {
    const float* x     = (const float*)d_in[0];
    const float* st    = (const float*)d_in[1];
    const float* hs0   = (const float*)d_in[2];
    const float* cs0   = (const float*)d_in[3];
    const float* W_ih  = (const float*)d_in[4];
    const float* W_hh  = (const float*)d_in[5];
    const float* b_ih  = (const float*)d_in[6];
    const float* b_hh  = (const float*)d_in[7];
    const float* W_lin = (const float*)d_in[8];
    const float* b_lin = (const float*)d_in[9];
    float* out = (float*)d_out;

    lstm_fused_kernel<<<dim3(B_ / 16), dim3(512), 0, stream>>>(
        x, st, hs0, cs0, W_ih, W_hh, b_ih, b_hh, W_lin, b_lin, out);
}